// Round 2
// baseline (506.568 us; speedup 1.0000x reference)
//
#include <hip/hip_runtime.h>
#include <hip/hip_bf16.h>

typedef __hip_bfloat16 bf16;

namespace {
constexpr int NT = 256;       // threads per block
constexpr int NPIX = 225;     // 15*15
constexpr int D = 48;
constexpr int NP = 16;        // policy channels
constexpr int NV = 32;        // value channels
constexpr int PCODE_C = 2380;

// shared memory layout (byte offsets)
constexpr int OFF_A = 0;          // 10800 bf16 = 21600 B (pre-conv feat; later PolA/PolB/s_part alias)
constexpr int OFF_B = 21600;      // 10800 bf16 = 21600 B (post-conv feat)
constexpr int OFF_CODES = 43200;  // 225 int = 900 B (pad to 912)
constexpr int OFF_W = 44112;      // 1984 f32 = 7936 B
constexpr int OFF_SMALL = 52048;  // s_v(32) h1(32) h2(32) f32 = 384 B
constexpr int SMEM_BYTES = 52448;

// weight region sub-offsets (in floats)
constexpr int W_CONVW = 0;    // 48*9 = 432
constexpr int W_CONVB = 432;  // 48
constexpr int W_PPW   = 480;  // 16*16 = 256
constexpr int W_PPWB  = 736;  // 16
constexpr int W_PDW   = 752;  // 16*9 = 144
constexpr int W_PDWB  = 896;  // 16
constexpr int W_PF    = 912;  // 16
constexpr int W_VPW   = 928;  // 32*32 = 1024
constexpr int W_VPWB  = 1952; // 32 -> total 1984
}

__device__ __forceinline__ float b2f(bf16 x) { return __bfloat162float(x); }
__device__ __forceinline__ bf16 f2b(float x) { return __float2bfloat16(x); }

__global__ __launch_bounds__(NT) void patnet_kernel(
    const float* __restrict__ emb,
    const float* __restrict__ conv_w, const float* __restrict__ conv_b,
    const float* __restrict__ ppw_w,  const float* __restrict__ ppw_b,
    const float* __restrict__ pdw_w,  const float* __restrict__ pdw_b,
    const float* __restrict__ pf_w,
    const float* __restrict__ vpw_w,  const float* __restrict__ vpw_b,
    const float* __restrict__ vl1_w,  const float* __restrict__ vl1_b,
    const float* __restrict__ vl2_w,  const float* __restrict__ vl2_b,
    const float* __restrict__ vf_w,   const float* __restrict__ vf_b,
    const int* __restrict__ sparse,   const int* __restrict__ board,
    float* __restrict__ out, int batch)
{
    __shared__ __align__(16) unsigned char smem[SMEM_BYTES];
    bf16* A      = (bf16*)(smem + OFF_A);
    bf16* Bf     = (bf16*)(smem + OFF_B);
    int*  codes  = (int*)(smem + OFF_CODES);
    float* w     = (float*)(smem + OFF_W);
    float* s_v   = (float*)(smem + OFF_SMALL);
    float* h1    = s_v + 32;
    float* h2    = h1 + 32;
    bf16* PolA   = A;               // 16*225 bf16 = 7200 B (A dead after phase 2)
    bf16* PolB   = A + NP * NPIX;   // next 7200 B
    float* s_part = (float*)(smem + OFF_A);  // 1024 B, used in phase 6 (Pol dead)

    const int tid = threadIdx.x;
    const int b   = blockIdx.x;

    // ---- phase 0: stage weights (fp32) + codes into LDS ----
    for (int i = tid; i < 432;  i += NT) w[W_CONVW + i] = conv_w[i];
    for (int i = tid; i < 48;   i += NT) w[W_CONVB + i] = conv_b[i];
    for (int i = tid; i < 256;  i += NT) w[W_PPW  + i]  = ppw_w[i];
    for (int i = tid; i < 16;   i += NT) w[W_PPWB + i]  = ppw_b[i];
    for (int i = tid; i < 144;  i += NT) w[W_PDW  + i]  = pdw_w[i];
    for (int i = tid; i < 16;   i += NT) w[W_PDWB + i]  = pdw_b[i];
    for (int i = tid; i < 16;   i += NT) w[W_PF   + i]  = pf_w[i];
    for (int i = tid; i < 1024; i += NT) w[W_VPW  + i]  = vpw_w[i];
    for (int i = tid; i < 32;   i += NT) w[W_VPWB + i]  = vpw_b[i];

    if (tid < NPIX) {
        int s10 = sparse[b * 2700 + 10 * NPIX + tid];
        int s11 = sparse[b * 2700 + 11 * NPIX + tid];
        int b0  = board[b * 450 + tid];
        int b1  = board[b * 450 + NPIX + tid];
        int c0 = (b0 > 0) ? PCODE_C : s10;
        int c1 = ((b1 > 0) ? PCODE_C : s11) + (PCODE_C + 1);
        codes[tid] = c0 | (c1 << 16);   // c0<2381 fits 16b, c1<4762 fits 15b
    }
    __syncthreads();

    // ---- phase 1: embedding gather + sum -> A[c*225+p] ----
    for (int idx = tid; idx < D * NPIX; idx += NT) {
        int p = idx / D;
        int c = idx - p * D;
        int pk = codes[p];
        int c0 = pk & 0xFFFF, c1 = pk >> 16;
        float v = emb[c0 * D + c] + emb[c1 * D + c];
        A[c * NPIX + p] = f2b(v);
    }
    __syncthreads();

    // ---- phase 2: depthwise 3x3 (groups=48) + bias + relu : A -> Bf ----
    for (int idx = tid; idx < D * NPIX; idx += NT) {
        int c = idx / NPIX;
        int p = idx - c * NPIX;
        int y = p / 15, x = p - y * 15;
        float acc = w[W_CONVB + c];
        #pragma unroll
        for (int ky = 0; ky < 3; ky++) {
            int yy = y + ky - 1;
            if ((unsigned)yy < 15u) {
                #pragma unroll
                for (int kx = 0; kx < 3; kx++) {
                    int xx = x + kx - 1;
                    if ((unsigned)xx < 15u)
                        acc += b2f(A[c * NPIX + yy * 15 + xx]) * w[W_CONVW + c * 9 + ky * 3 + kx];
                }
            }
        }
        Bf[c * NPIX + p] = f2b(fmaxf(acc, 0.f));
    }
    __syncthreads();

    // ---- phase 3: policy 1x1 16->16 + bias + relu : Bf[0:16] -> PolA ----
    for (int idx = tid; idx < NP * NPIX; idx += NT) {
        int oc = idx / NPIX;
        int p  = idx - oc * NPIX;
        float acc = w[W_PPWB + oc];
        #pragma unroll
        for (int ic = 0; ic < NP; ic++)
            acc += b2f(Bf[ic * NPIX + p]) * w[W_PPW + oc * NP + ic];
        PolA[oc * NPIX + p] = f2b(fmaxf(acc, 0.f));
    }
    __syncthreads();

    // ---- phase 4: policy depthwise 3x3 + bias + relu : PolA -> PolB ----
    for (int idx = tid; idx < NP * NPIX; idx += NT) {
        int c = idx / NPIX;
        int p = idx - c * NPIX;
        int y = p / 15, x = p - y * 15;
        float acc = w[W_PDWB + c];
        #pragma unroll
        for (int ky = 0; ky < 3; ky++) {
            int yy = y + ky - 1;
            if ((unsigned)yy < 15u) {
                #pragma unroll
                for (int kx = 0; kx < 3; kx++) {
                    int xx = x + kx - 1;
                    if ((unsigned)xx < 15u)
                        acc += b2f(PolA[c * NPIX + yy * 15 + xx]) * w[W_PDW + c * 9 + ky * 3 + kx];
                }
            }
        }
        PolB[c * NPIX + p] = f2b(fmaxf(acc, 0.f));
    }
    __syncthreads();

    // ---- phase 5: policy final 1x1 16->1 (no bias), store ----
    if (tid < NPIX) {
        float acc = 0.f;
        #pragma unroll
        for (int c = 0; c < NP; c++)
            acc += b2f(PolB[c * NPIX + tid]) * w[W_PF + c];
        out[3 * batch + b * NPIX + tid] = acc;
    }
    __syncthreads();

    // ---- phase 6: value 1x1 32->32 + bias + relu, mean over pixels ----
    {
        int vc = tid >> 3;   // 0..31
        int j  = tid & 7;
        float vsum = 0.f;
        for (int p = j; p < NPIX; p += 8) {
            float acc = w[W_VPWB + vc];
            #pragma unroll
            for (int ic = 0; ic < NV; ic++)
                acc += b2f(Bf[(NP + ic) * NPIX + p]) * w[W_VPW + vc * NV + ic];
            vsum += fmaxf(acc, 0.f);
        }
        s_part[tid] = vsum;   // aliases dead Pol region
    }
    __syncthreads();
    if (tid < NV) {
        float s = 0.f;
        #pragma unroll
        for (int k = 0; k < 8; k++) s += s_part[tid * 8 + k];
        s_v[tid] = s * (1.f / 225.f);
    }
    __syncthreads();

    // ---- phase 7: FC 32->32 relu, 32->32 relu, 32->3 ----
    if (tid < NV) {
        float acc = vl1_b[tid];
        #pragma unroll
        for (int i = 0; i < NV; i++) acc += s_v[i] * vl1_w[tid * NV + i];
        h1[tid] = fmaxf(acc, 0.f);
    }
    __syncthreads();
    if (tid < NV) {
        float acc = vl2_b[tid];
        #pragma unroll
        for (int i = 0; i < NV; i++) acc += h1[i] * vl2_w[tid * NV + i];
        h2[tid] = fmaxf(acc, 0.f);
    }
    __syncthreads();
    if (tid < 3) {
        float acc = vf_b[tid];
        #pragma unroll
        for (int i = 0; i < NV; i++) acc += h2[i] * vf_w[tid * NV + i];
        out[b * 3 + tid] = acc;
    }
}

extern "C" void kernel_launch(void* const* d_in, const int* in_sizes, int n_in,
                              void* d_out, int out_size, void* d_ws, size_t ws_size,
                              hipStream_t stream) {
    const float* emb    = (const float*)d_in[0];
    const float* conv_w = (const float*)d_in[1];
    const float* conv_b = (const float*)d_in[2];
    const float* ppw_w  = (const float*)d_in[3];
    const float* ppw_b  = (const float*)d_in[4];
    const float* pdw_w  = (const float*)d_in[5];
    const float* pdw_b  = (const float*)d_in[6];
    const float* pf_w   = (const float*)d_in[7];
    const float* vpw_w  = (const float*)d_in[8];
    const float* vpw_b  = (const float*)d_in[9];
    const float* vl1_w  = (const float*)d_in[10];
    const float* vl1_b  = (const float*)d_in[11];
    const float* vl2_w  = (const float*)d_in[12];
    const float* vl2_b  = (const float*)d_in[13];
    const float* vf_w   = (const float*)d_in[14];
    const float* vf_b   = (const float*)d_in[15];
    const int* sparse   = (const int*)d_in[16];
    const int* board    = (const int*)d_in[17];
    float* out = (float*)d_out;

    int batch = in_sizes[16] / 2700;  // 4096
    patnet_kernel<<<batch, NT, 0, stream>>>(
        emb, conv_w, conv_b, ppw_w, ppw_b, pdw_w, pdw_b, pf_w,
        vpw_w, vpw_b, vl1_w, vl1_b, vl2_w, vl2_b, vf_w, vf_b,
        sparse, board, out, batch);
}

// Round 3
// 415.557 us; speedup vs baseline: 1.2190x; 1.2190x over previous
//
#include <hip/hip_runtime.h>
#include <hip/hip_bf16.h>

typedef __hip_bfloat16 bf16;
typedef short bf16x8 __attribute__((ext_vector_type(8)));   // 8 bf16 in 4 VGPRs (guide §3)
typedef float f32x4 __attribute__((ext_vector_type(4)));

namespace {
constexpr int NT = 256;       // 4 waves
constexpr int NPIX = 225;
constexpr int D = 48;
constexpr int NP = 16;
constexpr int NV = 32;
constexpr int PCODE_C = 2380;

// ---- LDS layout (byte offsets, all 16-aligned) ----
constexpr int OFF_A     = 0;       // pre-conv feat [225][48] bf16 = 21600 B
                                   //   aliased later: PolA[16][225] bf16 @0 (7200),
                                   //   PolB @7200 (7200), s_part 32x33 f32 @14400 (4224)
constexpr int OFF_X     = 21600;   // post-conv feat [240][48] bf16 = 23040 B (rows 225..239 zero)
constexpr int OFF_CODES = 44640;   // 225 int -> 912 B
constexpr int OFF_W     = 45552;   // 656 f32 = 2624 B
constexpr int OFF_WP    = 48176;   // policy pw weights bf16 [16][32] (ic>=16 zero) = 1024 B
constexpr int OFF_WV    = 49200;   // value pw weights bf16 [32][32] = 2048 B
constexpr int OFF_PB    = 51248;   // ppw_b f32[16] = 64 B
constexpr int OFF_VB    = 51312;   // vpw_b f32[32] = 128 B
constexpr int OFF_SMALL = 51440;   // s_v/h1/h2 f32[96] = 384 B
constexpr int SMEM_BYTES = 51824;

// fp32 weight region sub-offsets (floats)
constexpr int W_CONVW = 0;    // 48*9 = 432
constexpr int W_CONVB = 432;  // 48
constexpr int W_PDW   = 480;  // 16*9 = 144
constexpr int W_PDWB  = 624;  // 16
constexpr int W_PF    = 640;  // 16  -> 656 total
}

__device__ __forceinline__ float b2f(bf16 x) { return __bfloat162float(x); }
__device__ __forceinline__ bf16 f2b(float x) { return __float2bfloat16(x); }

__global__ __launch_bounds__(NT) void patnet_kernel(
    const float* __restrict__ emb,
    const float* __restrict__ conv_w, const float* __restrict__ conv_b,
    const float* __restrict__ ppw_w,  const float* __restrict__ ppw_b,
    const float* __restrict__ pdw_w,  const float* __restrict__ pdw_b,
    const float* __restrict__ pf_w,
    const float* __restrict__ vpw_w,  const float* __restrict__ vpw_b,
    const float* __restrict__ vl1_w,  const float* __restrict__ vl1_b,
    const float* __restrict__ vl2_w,  const float* __restrict__ vl2_b,
    const float* __restrict__ vf_w,   const float* __restrict__ vf_b,
    const int* __restrict__ sparse,   const int* __restrict__ board,
    float* __restrict__ out, int batch)
{
    __shared__ __align__(16) unsigned char smem[SMEM_BYTES];
    bf16*  A      = (bf16*)(smem + OFF_A);      // [p][48]
    bf16*  X      = (bf16*)(smem + OFF_X);      // [p][48], 240 rows
    int*   codes  = (int*)(smem + OFF_CODES);
    float* w      = (float*)(smem + OFF_W);
    bf16*  Wp     = (bf16*)(smem + OFF_WP);     // [16][32]
    bf16*  Wv     = (bf16*)(smem + OFF_WV);     // [32][32]
    float* pbias  = (float*)(smem + OFF_PB);
    float* vbias  = (float*)(smem + OFF_VB);
    float* s_v    = (float*)(smem + OFF_SMALL);
    float* h1     = s_v + 32;
    float* h2     = h1 + 32;
    bf16*  PolA   = (bf16*)(smem + 0);          // [16][225], aliases dead A
    bf16*  PolB   = (bf16*)(smem + 7200);
    float* s_part = (float*)(smem + 14400);     // [32][33] f32

    const int tid  = threadIdx.x;
    const int b    = blockIdx.x;
    const int lane = tid & 63;
    const int wave = tid >> 6;

    // ---- phase 0: stage weights + codes; zero X pad rows ----
    for (int i = tid; i < 432; i += NT) w[W_CONVW + i] = conv_w[i];
    for (int i = tid; i < 48;  i += NT) w[W_CONVB + i] = conv_b[i];
    for (int i = tid; i < 144; i += NT) w[W_PDW  + i]  = pdw_w[i];
    for (int i = tid; i < 16;  i += NT) w[W_PDWB + i]  = pdw_b[i];
    for (int i = tid; i < 16;  i += NT) w[W_PF   + i]  = pf_w[i];
    for (int i = tid; i < 512; i += NT) {          // Wp: [oc][ic0..31], ic>=16 -> 0
        int oc = i >> 5, ic = i & 31;
        Wp[i] = (ic < NP) ? f2b(ppw_w[oc * NP + ic]) : f2b(0.f);
    }
    for (int i = tid; i < 1024; i += NT) Wv[i] = f2b(vpw_w[i]);
    for (int i = tid; i < 16;  i += NT) pbias[i] = ppw_b[i];
    for (int i = tid; i < 32;  i += NT) vbias[i] = vpw_b[i];
    for (int i = tid; i < 15 * 48; i += NT) X[NPIX * 48 + i] = f2b(0.f);

    if (tid < NPIX) {
        int s10 = sparse[b * 2700 + 10 * NPIX + tid];
        int s11 = sparse[b * 2700 + 11 * NPIX + tid];
        int b0  = board[b * 450 + tid];
        int b1  = board[b * 450 + NPIX + tid];
        int c0 = (b0 > 0) ? PCODE_C : s10;
        int c1 = ((b1 > 0) ? PCODE_C : s11) + (PCODE_C + 1);
        codes[tid] = c0 | (c1 << 16);
    }
    __syncthreads();

    // ---- phase 1: embedding gather+sum -> A[p][c] ----
    for (int idx = tid; idx < D * NPIX; idx += NT) {
        int p = idx / D;
        int c = idx - p * D;
        int pk = codes[p];
        int c0 = pk & 0xFFFF, c1 = pk >> 16;
        A[p * D + c] = f2b(emb[c0 * D + c] + emb[c1 * D + c]);
    }
    __syncthreads();

    // ---- phase 2: depthwise 3x3 (48ch) + bias + relu : A[p][c] -> X[p][c] ----
    for (int idx = tid; idx < D * NPIX; idx += NT) {
        int p = idx / D;
        int c = idx - p * D;
        int y = p / 15, x = p - y * 15;
        float acc = w[W_CONVB + c];
        #pragma unroll
        for (int ky = 0; ky < 3; ky++) {
            int yy = y + ky - 1;
            if ((unsigned)yy < 15u) {
                #pragma unroll
                for (int kx = 0; kx < 3; kx++) {
                    int xx = x + kx - 1;
                    if ((unsigned)xx < 15u)
                        acc += b2f(A[(yy * 15 + xx) * D + c]) * w[W_CONVW + c * 9 + ky * 3 + kx];
                }
            }
        }
        X[p * D + c] = f2b(fmaxf(acc, 0.f));
    }
    __syncthreads();

    // ---- phase 3: policy 1x1 16->16 via MFMA (K=32, zero-padded weights) ----
    {
        const int n = lane & 15, q = lane >> 4;
        // A-frag: Wp[m=lane&15][k=8q+j]  (row stride 64 B)
        bf16x8 afrag = *(const bf16x8*)((const unsigned char*)Wp + (lane & 15) * 64 + q * 16);
        for (int t = wave; t < 15; t += 4) {
            int p = t * 16 + n;
            // B-frag: X[p][k=8q+j] (row stride 96 B; k = ic 0..31, policy ics 0..15)
            bf16x8 bfrag = *(const bf16x8*)(smem + OFF_X + p * 96 + q * 16);
            f32x4 d = __builtin_amdgcn_mfma_f32_16x16x32_bf16(afrag, bfrag, (f32x4)(0.f), 0, 0, 0);
            if (p < NPIX) {
                #pragma unroll
                for (int r = 0; r < 4; r++) {
                    int oc = q * 4 + r;   // D row = oc, col = pixel
                    PolA[oc * NPIX + p] = f2b(fmaxf(d[r] + pbias[oc], 0.f));
                }
            }
        }
    }
    __syncthreads();

    // ---- phase 4: policy depthwise 3x3 + bias + relu : PolA -> PolB ----
    for (int idx = tid; idx < NP * NPIX; idx += NT) {
        int c = idx / NPIX;
        int p = idx - c * NPIX;
        int y = p / 15, x = p - y * 15;
        float acc = w[W_PDWB + c];
        #pragma unroll
        for (int ky = 0; ky < 3; ky++) {
            int yy = y + ky - 1;
            if ((unsigned)yy < 15u) {
                #pragma unroll
                for (int kx = 0; kx < 3; kx++) {
                    int xx = x + kx - 1;
                    if ((unsigned)xx < 15u)
                        acc += b2f(PolA[c * NPIX + yy * 15 + xx]) * w[W_PDW + c * 9 + ky * 3 + kx];
                }
            }
        }
        PolB[c * NPIX + p] = f2b(fmaxf(acc, 0.f));
    }
    __syncthreads();

    // ---- phase 5: policy final 1x1 16->1, store ----
    if (tid < NPIX) {
        float acc = 0.f;
        #pragma unroll
        for (int c = 0; c < NP; c++)
            acc += b2f(PolB[c * NPIX + tid]) * w[W_PF + c];
        out[3 * batch + b * NPIX + tid] = acc;
    }
    // no sync needed: phase 6 writes s_part (disjoint from PolA/PolB/out), reads X (ready)

    // ---- phase 6: value 1x1 32->32 + bias + relu + mean via MFMA ----
    {
        const int n = lane & 15, q = lane >> 4;
        const int mt = wave >> 1;            // waves 0,1 -> oc 0..15 ; waves 2,3 -> oc 16..31
        // A-frag: Wv[mt*16 + m][k=8q+j]
        bf16x8 afrag = *(const bf16x8*)((const unsigned char*)Wv + (mt * 16 + (lane & 15)) * 64 + q * 16);
        float vacc[4] = {0.f, 0.f, 0.f, 0.f};
        for (int t = (wave & 1); t < 15; t += 2) {
            int p = t * 16 + n;
            // B-frag: X[p][16 + 8q+j]  (value channels 16..47)
            bf16x8 bfrag = *(const bf16x8*)(smem + OFF_X + p * 96 + 32 + q * 16);
            f32x4 d = __builtin_amdgcn_mfma_f32_16x16x32_bf16(afrag, bfrag, (f32x4)(0.f), 0, 0, 0);
            if (p < NPIX) {
                #pragma unroll
                for (int r = 0; r < 4; r++) {
                    int oc = mt * 16 + q * 4 + r;
                    vacc[r] += fmaxf(d[r] + vbias[oc], 0.f);
                }
            }
        }
        #pragma unroll
        for (int r = 0; r < 4; r++) {
            int oc = mt * 16 + q * 4 + r;
            s_part[oc * 33 + (wave & 1) * 16 + n] = vacc[r];
        }
    }
    __syncthreads();
    if (tid < NV) {
        float s = 0.f;
        #pragma unroll
        for (int c = 0; c < 32; c++) s += s_part[tid * 33 + c];
        s_v[tid] = s * (1.f / 225.f);
    }
    __syncthreads();

    // ---- phase 7: FC 32->32 relu, 32->32 relu, 32->3 ----
    if (tid < NV) {
        float acc = vl1_b[tid];
        #pragma unroll
        for (int i = 0; i < NV; i++) acc += s_v[i] * vl1_w[tid * NV + i];
        h1[tid] = fmaxf(acc, 0.f);
    }
    __syncthreads();
    if (tid < NV) {
        float acc = vl2_b[tid];
        #pragma unroll
        for (int i = 0; i < NV; i++) acc += h1[i] * vl2_w[tid * NV + i];
        h2[tid] = fmaxf(acc, 0.f);
    }
    __syncthreads();
    if (tid < 3) {
        float acc = vf_b[tid];
        #pragma unroll
        for (int i = 0; i < NV; i++) acc += h2[i] * vf_w[tid * NV + i];
        out[b * 3 + tid] = acc;
    }
}

extern "C" void kernel_launch(void* const* d_in, const int* in_sizes, int n_in,
                              void* d_out, int out_size, void* d_ws, size_t ws_size,
                              hipStream_t stream) {
    const float* emb    = (const float*)d_in[0];
    const float* conv_w = (const float*)d_in[1];
    const float* conv_b = (const float*)d_in[2];
    const float* ppw_w  = (const float*)d_in[3];
    const float* ppw_b  = (const float*)d_in[4];
    const float* pdw_w  = (const float*)d_in[5];
    const float* pdw_b  = (const float*)d_in[6];
    const float* pf_w   = (const float*)d_in[7];
    const float* vpw_w  = (const float*)d_in[8];
    const float* vpw_b  = (const float*)d_in[9];
    const float* vl1_w  = (const float*)d_in[10];
    const float* vl1_b  = (const float*)d_in[11];
    const float* vl2_w  = (const float*)d_in[12];
    const float* vl2_b  = (const float*)d_in[13];
    const float* vf_w   = (const float*)d_in[14];
    const float* vf_b   = (const float*)d_in[15];
    const int* sparse   = (const int*)d_in[16];
    const int* board    = (const int*)d_in[17];
    float* out = (float*)d_out;

    int batch = in_sizes[16] / 2700;  // 4096
    patnet_kernel<<<batch, NT, 0, stream>>>(
        emb, conv_w, conv_b, ppw_w, ppw_b, pdw_w, pdw_b, pf_w,
        vpw_w, vpw_b, vl1_w, vl1_b, vl2_w, vl2_b, vf_w, vf_b,
        sparse, board, out, batch);
}

// Round 5
// 219.695 us; speedup vs baseline: 2.3058x; 1.8915x over previous
//
#include <hip/hip_runtime.h>
#include <hip/hip_bf16.h>
#include <hip/hip_fp16.h>

typedef _Float16 half8  __attribute__((ext_vector_type(8)));
typedef _Float16 half4_t __attribute__((ext_vector_type(4)));
typedef _Float16 half2_t __attribute__((ext_vector_type(2)));
typedef float f32x4 __attribute__((ext_vector_type(4)));

namespace {
constexpr int NT = 256;
constexpr int NPIX = 225;
constexpr int NP = 16;
constexpr int NV = 32;
constexpr int PCODE_C = 2380;

// ---- LDS layout (byte offsets) ----
// A rows: 112 B (56 f16 slots, 48 used) -> 28 words, gcd(28,32)=4: conflict-free b128 @ pixel stride
// X rows: 96 B (48 f16) -> MFMA B-frag pattern (24n+4q)%32 covers all banks: conflict-free
// Pol rows: 48 B (24 f16 slots, 16 used) -> 12 words: conflict-free b128 @ pixel stride
constexpr int OFF_A     = 0;                 // 225*112 = 25200
constexpr int OFF_X     = 25200;             // 240*96  = 23040 (rows 225..239 garbage, discarded cols)
constexpr int OFF_CODES = 48240;             // 912
constexpr int OFF_WC    = 49152;             // dw conv w  f16 [6][9][8]  = 864
constexpr int OFF_WCB   = 50016;             // dw conv b  f16 [48]       = 96
constexpr int OFF_WPD   = 50112;             // pol dw w   f16 [2][9][8]  = 288
constexpr int OFF_WPDB  = 50400;             // pol dw b   f16 [16]       = 32
constexpr int OFF_WP    = 50432;             // ppw        f16 [16][32]   = 1024 (k>=16 zero)
constexpr int OFF_WV    = 51456;             // vpw        f16 [32][32]   = 2048
constexpr int OFF_PF    = 53504;             // pf         half2[8]       = 32
constexpr int OFF_PB    = 53536;             // ppw_b f32[16] = 64
constexpr int OFF_VB    = 53600;             // vpw_b f32[32] = 128
constexpr int OFF_SMALL = 53728;             // s_v/h1/h2 f32[96] = 384
constexpr int SMEM_BYTES = 54112;            // 3 blocks/CU (3*54112 < 160 KiB)

// aliases inside dead A region:
constexpr int OFF_POLA  = 0;                 // [225] rows of 48 B = 10800
constexpr int OFF_POLB  = 10800;             // 10800
// s_part f32[32][33] = 4224 aliases OFF_POLA after phase 4
}

__global__ __launch_bounds__(NT) void patnet_kernel(
    const float* __restrict__ emb,
    const float* __restrict__ conv_w, const float* __restrict__ conv_b,
    const float* __restrict__ ppw_w,  const float* __restrict__ ppw_b,
    const float* __restrict__ pdw_w,  const float* __restrict__ pdw_b,
    const float* __restrict__ pf_w,
    const float* __restrict__ vpw_w,  const float* __restrict__ vpw_b,
    const float* __restrict__ vl1_w,  const float* __restrict__ vl1_b,
    const float* __restrict__ vl2_w,  const float* __restrict__ vl2_b,
    const float* __restrict__ vf_w,   const float* __restrict__ vf_b,
    const int* __restrict__ sparse,   const int* __restrict__ board,
    float* __restrict__ out, int batch)
{
    __shared__ __align__(16) unsigned char smem[SMEM_BYTES];
    int*       codes = (int*)(smem + OFF_CODES);
    _Float16*  Wc    = (_Float16*)(smem + OFF_WC);
    _Float16*  Wcb   = (_Float16*)(smem + OFF_WCB);
    _Float16*  Wpd   = (_Float16*)(smem + OFF_WPD);
    _Float16*  Wpdb  = (_Float16*)(smem + OFF_WPDB);
    _Float16*  Wph   = (_Float16*)(smem + OFF_WP);
    _Float16*  Wvh   = (_Float16*)(smem + OFF_WV);
    half2_t*   pfh   = (half2_t*)(smem + OFF_PF);
    float*     pbias = (float*)(smem + OFF_PB);
    float*     vbias = (float*)(smem + OFF_VB);
    float*     s_v   = (float*)(smem + OFF_SMALL);
    float*     h1    = s_v + 32;
    float*     h2    = h1 + 32;
    float*     s_part = (float*)(smem + OFF_POLA);   // phase 6 (PolA dead)

    const int tid  = threadIdx.x;
    const int b    = blockIdx.x;
    const int lane = tid & 63;
    const int wave = tid >> 6;

    // ---- phase 0: stage weights (f16) + codes ----
    for (int i = tid; i < 432; i += NT) {            // Wc[cg][t][j] = conv_w[(cg*8+j)*9+t]
        int cg = i / 72, rem = i - cg * 72;
        int t = rem >> 3, j = rem & 7;
        Wc[i] = (_Float16)conv_w[(cg * 8 + j) * 9 + t];
    }
    for (int i = tid; i < 48;  i += NT) Wcb[i] = (_Float16)conv_b[i];
    for (int i = tid; i < 144; i += NT) {            // Wpd[cg][t][j] = pdw_w[(cg*8+j)*9+t]
        int cg = i / 72, rem = i - cg * 72;
        int t = rem >> 3, j = rem & 7;
        Wpd[i] = (_Float16)pdw_w[(cg * 8 + j) * 9 + t];
    }
    for (int i = tid; i < 16;  i += NT) Wpdb[i] = (_Float16)pdw_b[i];
    for (int i = tid; i < 512; i += NT) {            // Wp[oc][k], k>=16 zero
        int oc = i >> 5, ic = i & 31;
        Wph[i] = (ic < NP) ? (_Float16)ppw_w[oc * NP + ic] : (_Float16)0.f;
    }
    for (int i = tid; i < 1024; i += NT) Wvh[i] = (_Float16)vpw_w[i];
    if (tid < 8)  pfh[tid] = half2_t{(_Float16)pf_w[2 * tid], (_Float16)pf_w[2 * tid + 1]};
    if (tid < 16) pbias[tid] = ppw_b[tid];
    if (tid < 32) vbias[tid] = vpw_b[tid];

    if (tid < NPIX) {
        int s10 = sparse[b * 2700 + 10 * NPIX + tid];
        int s11 = sparse[b * 2700 + 11 * NPIX + tid];
        int b0  = board[b * 450 + tid];
        int b1  = board[b * 450 + NPIX + tid];
        int c0 = (b0 > 0) ? PCODE_C : s10;
        int c1 = ((b1 > 0) ? PCODE_C : s11) + (PCODE_C + 1);
        codes[tid] = c0 | (c1 << 16);
    }
    __syncthreads();

    // ---- phase 1: embedding gather+sum -> A[p][c] f16 (8-ch groups, float4 loads) ----
    for (int idx = tid; idx < 225 * 6; idx += NT) {
        int p = idx / 6, cg = idx - p * 6;
        int pk = codes[p];
        int c0 = pk & 0xFFFF, c1 = pk >> 16;
        const float* e0 = emb + c0 * 48 + cg * 8;
        const float* e1 = emb + c1 * 48 + cg * 8;
        f32x4 a0 = *(const f32x4*)e0, b0v = *(const f32x4*)(e0 + 4);
        f32x4 a1 = *(const f32x4*)e1, b1v = *(const f32x4*)(e1 + 4);
        f32x4 s0 = a0 + a1, s1 = b0v + b1v;
        half8 hv = {(_Float16)s0.x, (_Float16)s0.y, (_Float16)s0.z, (_Float16)s0.w,
                    (_Float16)s1.x, (_Float16)s1.y, (_Float16)s1.z, (_Float16)s1.w};
        *(half8*)(smem + OFF_A + p * 112 + cg * 16) = hv;
    }
    __syncthreads();

    // ---- phase 2: depthwise 3x3 (48ch) + bias + relu, packed f16: A -> X ----
    if (tid < 252) {
        int cg = tid % 6, prow = tid / 6;            // cg fixed per thread
        const _Float16* wb = Wc + cg * 72;
        half8 wv[9];
        #pragma unroll
        for (int t = 0; t < 9; t++) wv[t] = *(const half8*)(wb + t * 8);
        half8 bias = *(const half8*)(Wcb + cg * 8);
        for (int p = prow; p < NPIX; p += 42) {
            int y = p / 15, x = p - y * 15;
            half8 acc = bias;
            #pragma unroll
            for (int dy = -1; dy <= 1; dy++) {
                int yy = y + dy;
                if ((unsigned)yy >= 15u) continue;
                #pragma unroll
                for (int dx = -1; dx <= 1; dx++) {
                    int xx = x + dx;
                    if ((unsigned)xx >= 15u) continue;
                    half8 v = *(const half8*)(smem + OFF_A + (yy * 15 + xx) * 112 + cg * 16);
                    acc = __builtin_elementwise_fma(v, wv[(dy + 1) * 3 + (dx + 1)], acc);
                }
            }
            acc = __builtin_elementwise_max(acc, (half8)(_Float16)0.f);
            *(half8*)(smem + OFF_X + p * 96 + cg * 16) = acc;
        }
    }
    __syncthreads();

    // ---- phase 3: policy 1x1 16->16 via MFMA f16 (K=32 zero-padded) ----
    {
        const int n = lane & 15, q = lane >> 4;
        half8 afrag = *(const half8*)(Wph + (lane & 15) * 32 + q * 8);
        for (int t = wave; t < 15; t += 4) {
            int p = t * 16 + n;
            half8 bfrag = *(const half8*)(smem + OFF_X + p * 96 + q * 16);
            f32x4 d = __builtin_amdgcn_mfma_f32_16x16x32_f16(afrag, bfrag, (f32x4)(0.f), 0, 0, 0);
            if (p < NPIX) {
                float e0 = fmaxf(d[0] + pbias[q * 4 + 0], 0.f);
                float e1 = fmaxf(d[1] + pbias[q * 4 + 1], 0.f);
                float e2 = fmaxf(d[2] + pbias[q * 4 + 2], 0.f);
                float e3 = fmaxf(d[3] + pbias[q * 4 + 3], 0.f);
                half4_t hv = {(_Float16)e0, (_Float16)e1, (_Float16)e2, (_Float16)e3};
                *(half4_t*)(smem + OFF_POLA + p * 48 + q * 8) = hv;
            }
        }
    }
    __syncthreads();

    // ---- phase 4: policy depthwise 3x3 + bias + relu, packed f16 ----
    {
        int cg = tid & 1, prow = tid >> 1;
        const _Float16* wb = Wpd + cg * 72;
        half8 wv[9];
        #pragma unroll
        for (int t = 0; t < 9; t++) wv[t] = *(const half8*)(wb + t * 8);
        half8 bias = *(const half8*)(Wpdb + cg * 8);
        for (int p = prow; p < NPIX; p += 128) {
            int y = p / 15, x = p - y * 15;
            half8 acc = bias;
            #pragma unroll
            for (int dy = -1; dy <= 1; dy++) {
                int yy = y + dy;
                if ((unsigned)yy >= 15u) continue;
                #pragma unroll
                for (int dx = -1; dx <= 1; dx++) {
                    int xx = x + dx;
                    if ((unsigned)xx >= 15u) continue;
                    half8 v = *(const half8*)(smem + OFF_POLA + (yy * 15 + xx) * 48 + cg * 16);
                    acc = __builtin_elementwise_fma(v, wv[(dy + 1) * 3 + (dx + 1)], acc);
                }
            }
            acc = __builtin_elementwise_max(acc, (half8)(_Float16)0.f);
            *(half8*)(smem + OFF_POLB + p * 48 + cg * 16) = acc;
        }
    }
    __syncthreads();

    // ---- phase 5: policy final 1x1 16->1 via v_dot2_f32_f16, store ----
    if (tid < NPIX) {
        const half2_t* row = (const half2_t*)(smem + OFF_POLB + tid * 48);
        float acc = 0.f;
        #pragma unroll
        for (int j = 0; j < 8; j++)
            acc = __builtin_amdgcn_fdot2(row[j], pfh[j], acc, false);
        out[3 * batch + b * NPIX + tid] = acc;
    }
    // no barrier: phase 6 writes s_part (aliases dead PolA, disjoint from PolB/out), reads stable X

    // ---- phase 6: value 1x1 32->32 + bias + relu + mean via MFMA f16 ----
    {
        const int n = lane & 15, q = lane >> 4;
        const int mt = wave >> 1;
        half8 afrag = *(const half8*)(Wvh + (mt * 16 + (lane & 15)) * 32 + q * 8);
        f32x4 vacc = {0.f, 0.f, 0.f, 0.f};
        for (int t = (wave & 1); t < 15; t += 2) {
            int p = t * 16 + n;
            half8 bfrag = *(const half8*)(smem + OFF_X + p * 96 + 32 + q * 16);
            f32x4 d = __builtin_amdgcn_mfma_f32_16x16x32_f16(afrag, bfrag, (f32x4)(0.f), 0, 0, 0);
            if (p < NPIX) {
                #pragma unroll
                for (int r = 0; r < 4; r++)
                    vacc[r] += fmaxf(d[r] + vbias[mt * 16 + q * 4 + r], 0.f);
            }
        }
        #pragma unroll
        for (int r = 0; r < 4; r++)
            s_part[(mt * 16 + q * 4 + r) * 33 + (wave & 1) * 16 + n] = vacc[r];
    }
    __syncthreads();
    if (tid < NV) {
        float s = 0.f;
        #pragma unroll
        for (int c = 0; c < 32; c++) s += s_part[tid * 33 + c];
        s_v[tid] = s * (1.f / 225.f);
    }
    __syncthreads();

    // ---- phase 7: FC 32->32 relu, 32->32 relu, 32->3 ----
    if (tid < NV) {
        float acc = vl1_b[tid];
        #pragma unroll
        for (int i = 0; i < NV; i++) acc += s_v[i] * vl1_w[tid * NV + i];
        h1[tid] = fmaxf(acc, 0.f);
    }
    __syncthreads();
    if (tid < NV) {
        float acc = vl2_b[tid];
        #pragma unroll
        for (int i = 0; i < NV; i++) acc += h1[i] * vl2_w[tid * NV + i];
        h2[tid] = fmaxf(acc, 0.f);
    }
    __syncthreads();
    if (tid < 3) {
        float acc = vf_b[tid];
        #pragma unroll
        for (int i = 0; i < NV; i++) acc += h2[i] * vf_w[tid * NV + i];
        out[b * 3 + tid] = acc;
    }
}

extern "C" void kernel_launch(void* const* d_in, const int* in_sizes, int n_in,
                              void* d_out, int out_size, void* d_ws, size_t ws_size,
                              hipStream_t stream) {
    const float* emb    = (const float*)d_in[0];
    const float* conv_w = (const float*)d_in[1];
    const float* conv_b = (const float*)d_in[2];
    const float* ppw_w  = (const float*)d_in[3];
    const float* ppw_b  = (const float*)d_in[4];
    const float* pdw_w  = (const float*)d_in[5];
    const float* pdw_b  = (const float*)d_in[6];
    const float* pf_w   = (const float*)d_in[7];
    const float* vpw_w  = (const float*)d_in[8];
    const float* vpw_b  = (const float*)d_in[9];
    const float* vl1_w  = (const float*)d_in[10];
    const float* vl1_b  = (const float*)d_in[11];
    const float* vl2_w  = (const float*)d_in[12];
    const float* vl2_b  = (const float*)d_in[13];
    const float* vf_w   = (const float*)d_in[14];
    const float* vf_b   = (const float*)d_in[15];
    const int* sparse   = (const int*)d_in[16];
    const int* board    = (const int*)d_in[17];
    float* out = (float*)d_out;

    int batch = in_sizes[16] / 2700;  // 4096
    patnet_kernel<<<batch, NT, 0, stream>>>(
        emb, conv_w, conv_b, ppw_w, ppw_b, pdw_w, pdw_b, pf_w,
        vpw_w, vpw_b, vl1_w, vl1_b, vl2_w, vl2_b, vf_w, vf_b,
        sparse, board, out, batch);
}

// Round 6
// 178.362 us; speedup vs baseline: 2.8401x; 1.2317x over previous
//
#include <hip/hip_runtime.h>
#include <hip/hip_fp16.h>

typedef _Float16 half8  __attribute__((ext_vector_type(8)));
typedef _Float16 half4_t __attribute__((ext_vector_type(4)));
typedef _Float16 half2_t __attribute__((ext_vector_type(2)));
typedef float f32x4 __attribute__((ext_vector_type(4)));

namespace {
constexpr int NT = 256;
constexpr int NPIX = 225;
constexpr int PCODE_C = 2380;

// ---- LDS layout (byte offsets, 16-aligned) ----
constexpr int OFF_A     = 0;       // emb feat [225] rows of 112 B (48 f16 + pad) = 25200
constexpr int OFF_X     = 25200;   // post-conv [240] rows of 96 B (48 f16)       = 23040
constexpr int OFF_WC    = 48240;   // dw conv w  f16 [6][9][8]  = 864
constexpr int OFF_WCB   = 49104;   // dw conv b  f16 [48]       = 96
constexpr int OFF_WPD   = 49200;   // pol dw w   f16 [2][9][8]  = 288
constexpr int OFF_WPDB  = 49488;   // pol dw b   f16 [16]       = 32
constexpr int OFF_SV    = 49520;   // s_v f32[32]  = 128
constexpr int OFF_H1    = 49648;   // h1  f32[32]  = 128
constexpr int OFF_H2    = 49776;   // h2  f32[32]  = 128
constexpr int SMEM_BYTES = 49904;  // 3 blocks/CU

// aliases in dead A region (valid after ph2 barrier):
constexpr int OFF_POLA  = 0;       // [225] rows of 48 B (16 f16 + pad) = 10800
constexpr int OFF_POLB  = 10800;   // [225] rows of 32 B (16 f16)       = 7200
}

__device__ __forceinline__ void wave_fence() {
    // in-wave cross-lane LDS handoff: drain DS ops; lockstep wave => all lanes' writes done
    asm volatile("s_waitcnt lgkmcnt(0)" ::: "memory");
}

__global__ __launch_bounds__(NT) void patnet_kernel(
    const float* __restrict__ emb,
    const float* __restrict__ conv_w, const float* __restrict__ conv_b,
    const float* __restrict__ ppw_w,  const float* __restrict__ ppw_b,
    const float* __restrict__ pdw_w,  const float* __restrict__ pdw_b,
    const float* __restrict__ pf_w,
    const float* __restrict__ vpw_w,  const float* __restrict__ vpw_b,
    const float* __restrict__ vl1_w,  const float* __restrict__ vl1_b,
    const float* __restrict__ vl2_w,  const float* __restrict__ vl2_b,
    const float* __restrict__ vf_w,   const float* __restrict__ vf_b,
    const int* __restrict__ sparse,   const int* __restrict__ board,
    float* __restrict__ out, int batch)
{
    __shared__ __align__(16) unsigned char smem[SMEM_BYTES];
    const int tid  = threadIdx.x;
    const int b    = blockIdx.x;
    const int lane = tid & 63;
    const int wave = tid >> 6;

    // ---- P1a: issue this pixel's code loads early ----
    int c0 = 0, c1 = 0;
    if (tid < NPIX) {
        int s10 = sparse[b * 2700 + 10 * NPIX + tid];
        int s11 = sparse[b * 2700 + 11 * NPIX + tid];
        int b0  = board[b * 450 + tid];
        int b1  = board[b * 450 + NPIX + tid];
        c0 = (b0 > 0) ? PCODE_C : s10;
        c1 = ((b1 > 0) ? PCODE_C : s11) + (PCODE_C + 1);
    }

    // ---- P0: stage only the depthwise weight tables (transposed) ----
    {
        _Float16* Wc   = (_Float16*)(smem + OFF_WC);
        _Float16* Wcb  = (_Float16*)(smem + OFF_WCB);
        _Float16* Wpd  = (_Float16*)(smem + OFF_WPD);
        _Float16* Wpdb = (_Float16*)(smem + OFF_WPDB);
        for (int i = tid; i < 432; i += NT) {     // Wc[cg][t][j] = conv_w[(cg*8+j)*9+t]
            int cg = i / 72, rem = i - cg * 72;
            int t = rem >> 3, j = rem & 7;
            Wc[i] = (_Float16)conv_w[(cg * 8 + j) * 9 + t];
        }
        for (int i = tid; i < 48; i += NT) Wcb[i] = (_Float16)conv_b[i];
        for (int i = tid; i < 144; i += NT) {
            int cg = i / 72, rem = i - cg * 72;
            int t = rem >> 3, j = rem & 7;
            Wpd[i] = (_Float16)pdw_w[(cg * 8 + j) * 9 + t];
        }
        for (int i = tid; i < 16; i += NT) Wpdb[i] = (_Float16)pdw_b[i];
    }

    // ---- P1b: full-pixel embedding gather + sum -> A[p][48] f16 ----
    if (tid < NPIX) {
        const float* e0 = emb + c0 * 48;
        const float* e1 = emb + c1 * 48;
        #pragma unroll
        for (int g = 0; g < 6; g++) {
            f32x4 x0 = *(const f32x4*)(e0 + g * 8);
            f32x4 x1 = *(const f32x4*)(e0 + g * 8 + 4);
            f32x4 y0 = *(const f32x4*)(e1 + g * 8);
            f32x4 y1 = *(const f32x4*)(e1 + g * 8 + 4);
            f32x4 s0 = x0 + y0, s1 = x1 + y1;
            half8 hv = {(_Float16)s0.x, (_Float16)s0.y, (_Float16)s0.z, (_Float16)s0.w,
                        (_Float16)s1.x, (_Float16)s1.y, (_Float16)s1.z, (_Float16)s1.w};
            *(half8*)(smem + OFF_A + tid * 112 + g * 16) = hv;
        }
    }
    __syncthreads();

    // ---- P2: depthwise 3x3 (48ch) + bias + relu : A -> X ----
    if (tid < 252) {
        int cg = tid % 6, prow = tid / 6;
        const _Float16* wb = (const _Float16*)(smem + OFF_WC) + cg * 72;
        half8 wv[9];
        #pragma unroll
        for (int t = 0; t < 9; t++) wv[t] = *(const half8*)(wb + t * 8);
        half8 bias = *(const half8*)((const _Float16*)(smem + OFF_WCB) + cg * 8);
        for (int p = prow; p < NPIX; p += 42) {
            int y = p / 15, x = p - y * 15;
            half8 acc = bias;
            #pragma unroll
            for (int dy = -1; dy <= 1; dy++) {
                int yy = y + dy;
                if ((unsigned)yy >= 15u) continue;
                #pragma unroll
                for (int dx = -1; dx <= 1; dx++) {
                    int xx = x + dx;
                    if ((unsigned)xx >= 15u) continue;
                    half8 v = *(const half8*)(smem + OFF_A + (yy * 15 + xx) * 112 + cg * 16);
                    acc = __builtin_elementwise_fma(v, wv[(dy + 1) * 3 + (dx + 1)], acc);
                }
            }
            acc = __builtin_elementwise_max(acc, (half8)(_Float16)0.f);
            *(half8*)(smem + OFF_X + p * 96 + cg * 16) = acc;
        }
    }
    __syncthreads();

    // ================= head split: NO MORE BLOCK BARRIERS =================
    const int n = lane & 15, q = lane >> 4;

    if (wave < 3) {
        // ---------------- policy path (waves 0,1,2) ----------------
        // ph3: 1x1 16->16 via MFMA; each wave computes every tile its ph4 rows need
        half8 af;
        {
            const float* wp = ppw_w + n * 16 + (q & 1) * 8;
            f32x4 w0 = *(const f32x4*)wp;
            f32x4 w1 = *(const f32x4*)(wp + 4);
            half8 t = {(_Float16)w0.x, (_Float16)w0.y, (_Float16)w0.z, (_Float16)w0.w,
                       (_Float16)w1.x, (_Float16)w1.y, (_Float16)w1.z, (_Float16)w1.w};
            af = (q < 2) ? t : (half8)(_Float16)0.f;   // K zero-pad 16..31
        }
        f32x4 pb = *(const f32x4*)(ppw_b + q * 4);
        const int tlo = (wave == 0) ? 0 : ((wave == 1) ? 3 : 8);
        const int thi = (wave == 0) ? 6 : ((wave == 1) ? 11 : 15);
        for (int t = tlo; t < thi; t++) {
            int p = t * 16 + n;
            half8 bf = *(const half8*)(smem + OFF_X + p * 96 + q * 16);
            f32x4 d = __builtin_amdgcn_mfma_f32_16x16x32_f16(af, bf, (f32x4)(0.f), 0, 0, 0);
            if (p < NPIX) {
                half4_t hv = {(_Float16)fmaxf(d.x + pb.x, 0.f),
                              (_Float16)fmaxf(d.y + pb.y, 0.f),
                              (_Float16)fmaxf(d.z + pb.z, 0.f),
                              (_Float16)fmaxf(d.w + pb.w, 0.f)};
                *(half4_t*)(smem + OFF_POLA + p * 48 + q * 8) = hv;
            }
        }
        wave_fence();

        // ph4: policy depthwise 3x3, wave w owns rows 5w..5w+4 (px0..px0+74)
        const int px0 = wave * 75;
        {
            int cg = lane & 1;
            const _Float16* wb = (const _Float16*)(smem + OFF_WPD) + cg * 72;
            half8 wv[9];
            #pragma unroll
            for (int t = 0; t < 9; t++) wv[t] = *(const half8*)(wb + t * 8);
            half8 bias = *(const half8*)((const _Float16*)(smem + OFF_WPDB) + cg * 8);
            for (int i = 0; i < 3; i++) {
                int idx = i * 64 + lane;
                if (idx < 150) {
                    int px = px0 + (idx >> 1);
                    int y = px / 15, x = px - y * 15;
                    half8 acc = bias;
                    #pragma unroll
                    for (int dy = -1; dy <= 1; dy++) {
                        int yy = y + dy;
                        if ((unsigned)yy >= 15u) continue;
                        #pragma unroll
                        for (int dx = -1; dx <= 1; dx++) {
                            int xx = x + dx;
                            if ((unsigned)xx >= 15u) continue;
                            half8 v = *(const half8*)(smem + OFF_POLA + (yy * 15 + xx) * 48 + cg * 16);
                            acc = __builtin_elementwise_fma(v, wv[(dy + 1) * 3 + (dx + 1)], acc);
                        }
                    }
                    acc = __builtin_elementwise_max(acc, (half8)(_Float16)0.f);
                    *(half8*)(smem + OFF_POLB + px * 32 + cg * 16) = acc;
                }
            }
        }
        wave_fence();

        // ph5: 1x1 16->1 via fdot2; pf uniform (scalar loads)
        {
            half2_t pf[8];
            #pragma unroll
            for (int j = 0; j < 8; j++)
                pf[j] = half2_t{(_Float16)pf_w[2 * j], (_Float16)pf_w[2 * j + 1]};
            for (int i = 0; i < 2; i++) {
                int off = i * 64 + lane;
                if (off < 75) {
                    int px = px0 + off;
                    half8 u0 = *(const half8*)(smem + OFF_POLB + px * 32);
                    half8 u1 = *(const half8*)(smem + OFF_POLB + px * 32 + 16);
                    float acc = 0.f;
                    acc = __builtin_amdgcn_fdot2(half2_t{u0[0], u0[1]}, pf[0], acc, false);
                    acc = __builtin_amdgcn_fdot2(half2_t{u0[2], u0[3]}, pf[1], acc, false);
                    acc = __builtin_amdgcn_fdot2(half2_t{u0[4], u0[5]}, pf[2], acc, false);
                    acc = __builtin_amdgcn_fdot2(half2_t{u0[6], u0[7]}, pf[3], acc, false);
                    acc = __builtin_amdgcn_fdot2(half2_t{u1[0], u1[1]}, pf[4], acc, false);
                    acc = __builtin_amdgcn_fdot2(half2_t{u1[2], u1[3]}, pf[5], acc, false);
                    acc = __builtin_amdgcn_fdot2(half2_t{u1[4], u1[5]}, pf[6], acc, false);
                    acc = __builtin_amdgcn_fdot2(half2_t{u1[6], u1[7]}, pf[7], acc, false);
                    out[3 * batch + b * NPIX + px] = acc;
                }
            }
        }
    } else {
        // ---------------- value path (wave 3, whole head in-wave) ----------------
        half8 af0, af1;
        {
            const float* wp = vpw_w + n * 32 + q * 8;
            f32x4 w0 = *(const f32x4*)wp, w1 = *(const f32x4*)(wp + 4);
            af0 = half8{(_Float16)w0.x, (_Float16)w0.y, (_Float16)w0.z, (_Float16)w0.w,
                        (_Float16)w1.x, (_Float16)w1.y, (_Float16)w1.z, (_Float16)w1.w};
            const float* wp2 = vpw_w + (16 + n) * 32 + q * 8;
            f32x4 v0 = *(const f32x4*)wp2, v1 = *(const f32x4*)(wp2 + 4);
            af1 = half8{(_Float16)v0.x, (_Float16)v0.y, (_Float16)v0.z, (_Float16)v0.w,
                        (_Float16)v1.x, (_Float16)v1.y, (_Float16)v1.z, (_Float16)v1.w};
        }
        f32x4 vb0 = *(const f32x4*)(vpw_b + q * 4);
        f32x4 vb1 = *(const f32x4*)(vpw_b + 16 + q * 4);
        f32x4 a0 = {0.f, 0.f, 0.f, 0.f}, a1 = {0.f, 0.f, 0.f, 0.f};
        for (int t = 0; t < 15; t++) {
            int p = t * 16 + n;
            half8 bf = *(const half8*)(smem + OFF_X + p * 96 + 32 + q * 16);
            f32x4 d0 = __builtin_amdgcn_mfma_f32_16x16x32_f16(af0, bf, (f32x4)(0.f), 0, 0, 0);
            f32x4 d1 = __builtin_amdgcn_mfma_f32_16x16x32_f16(af1, bf, (f32x4)(0.f), 0, 0, 0);
            if (p < NPIX) {
                #pragma unroll
                for (int r = 0; r < 4; r++) {
                    a0[r] += fmaxf(d0[r] + vb0[r], 0.f);
                    a1[r] += fmaxf(d1[r] + vb1[r], 0.f);
                }
            }
        }
        // reduce over n (lane bits 0..3)
        #pragma unroll
        for (int s = 1; s < 16; s <<= 1) {
            #pragma unroll
            for (int r = 0; r < 4; r++) {
                a0[r] += __shfl_xor(a0[r], s, 64);
                a1[r] += __shfl_xor(a1[r], s, 64);
            }
        }
        if (n == 0) {
            f32x4 m0 = a0 * (1.f / 225.f), m1 = a1 * (1.f / 225.f);
            *(f32x4*)(smem + OFF_SV + q * 16) = m0;
            *(f32x4*)(smem + OFF_SV + 64 + q * 16) = m1;
        }
        wave_fence();

        int o = lane & 31;
        float acc1 = vl1_b[o];
        #pragma unroll
        for (int g = 0; g < 8; g++) {
            f32x4 sv = *(const f32x4*)(smem + OFF_SV + g * 16);
            f32x4 w4 = *(const f32x4*)(vl1_w + o * 32 + g * 4);
            acc1 += sv.x * w4.x + sv.y * w4.y + sv.z * w4.z + sv.w * w4.w;
        }
        acc1 = fmaxf(acc1, 0.f);
        if (lane < 32) *(float*)(smem + OFF_H1 + o * 4) = acc1;
        wave_fence();

        float acc2 = vl2_b[o];
        #pragma unroll
        for (int g = 0; g < 8; g++) {
            f32x4 hv = *(const f32x4*)(smem + OFF_H1 + g * 16);
            f32x4 w4 = *(const f32x4*)(vl2_w + o * 32 + g * 4);
            acc2 += hv.x * w4.x + hv.y * w4.y + hv.z * w4.z + hv.w * w4.w;
        }
        acc2 = fmaxf(acc2, 0.f);
        if (lane < 32) *(float*)(smem + OFF_H2 + o * 4) = acc2;
        wave_fence();

        if (lane < 3) {
            float acc3 = vf_b[lane];
            #pragma unroll
            for (int g = 0; g < 8; g++) {
                f32x4 hv = *(const f32x4*)(smem + OFF_H2 + g * 16);
                f32x4 w4 = *(const f32x4*)(vf_w + lane * 32 + g * 4);
                acc3 += hv.x * w4.x + hv.y * w4.y + hv.z * w4.z + hv.w * w4.w;
            }
            out[b * 3 + lane] = acc3;
        }
    }
}

extern "C" void kernel_launch(void* const* d_in, const int* in_sizes, int n_in,
                              void* d_out, int out_size, void* d_ws, size_t ws_size,
                              hipStream_t stream) {
    const float* emb    = (const float*)d_in[0];
    const float* conv_w = (const float*)d_in[1];
    const float* conv_b = (const float*)d_in[2];
    const float* ppw_w  = (const float*)d_in[3];
    const float* ppw_b  = (const float*)d_in[4];
    const float* pdw_w  = (const float*)d_in[5];
    const float* pdw_b  = (const float*)d_in[6];
    const float* pf_w   = (const float*)d_in[7];
    const float* vpw_w  = (const float*)d_in[8];
    const float* vpw_b  = (const float*)d_in[9];
    const float* vl1_w  = (const float*)d_in[10];
    const float* vl1_b  = (const float*)d_in[11];
    const float* vl2_w  = (const float*)d_in[12];
    const float* vl2_b  = (const float*)d_in[13];
    const float* vf_w   = (const float*)d_in[14];
    const float* vf_b   = (const float*)d_in[15];
    const int* sparse   = (const int*)d_in[16];
    const int* board    = (const int*)d_in[17];
    float* out = (float*)d_out;

    int batch = in_sizes[16] / 2700;  // 4096
    patnet_kernel<<<batch, NT, 0, stream>>>(
        emb, conv_w, conv_b, ppw_w, ppw_b, pdw_w, pdw_b, pf_w,
        vpw_w, vpw_b, vl1_w, vl1_b, vl2_w, vl2_b, vf_w, vf_b,
        sparse, board, out, batch);
}

// Round 7
// 174.413 us; speedup vs baseline: 2.9044x; 1.0226x over previous
//
#include <hip/hip_runtime.h>
#include <hip/hip_fp16.h>

typedef _Float16 half8  __attribute__((ext_vector_type(8)));
typedef _Float16 half4_t __attribute__((ext_vector_type(4)));
typedef _Float16 half2_t __attribute__((ext_vector_type(2)));
typedef __fp16   fp16x2  __attribute__((ext_vector_type(2)));
typedef float f32x4 __attribute__((ext_vector_type(4)));

namespace {
constexpr int NT = 256;
constexpr int NPIX = 225;
constexpr int PCODE_C = 2380;

// A_pad[6][17][17] half8 slots (16 B each): row pitch 272 B, cg pitch 4624 B
constexpr int APITCH_Y  = 272;
constexpr int APITCH_CG = 4624;

// ---- LDS layout (byte offsets, 16-aligned) ----
constexpr int OFF_A     = 0;       // 6*4624 = 27744 (zero-padded borders)
constexpr int OFF_X     = 27744;   // [240 rows][96 B] = 23040 (rows 225+ garbage, discarded)
constexpr int OFF_WC    = 50784;   // dw conv w  f16 [6][9][8]  = 864
constexpr int OFF_WCB   = 51648;   // dw conv b  f16 [6][8]     = 96
constexpr int OFF_WPD   = 51744;   // pol dw w   f16 [2][9][8]  = 288
constexpr int OFF_WPDB  = 52032;   // pol dw b   f16 [2][8]     = 32
constexpr int OFF_SV    = 52064;   // f32[32] = 128
constexpr int OFF_H1    = 52192;   // f32[32] = 128
constexpr int OFF_H2    = 52320;   // f32[32] = 128
constexpr int SMEM_BYTES = 52448;  // 3 blocks/CU (3*52448 = 157344 < 160 KiB)

// PolA_pad[2][17][17] half8 slots, aliases dead A region after barrier 2
constexpr int OFF_POLA  = 0;       // 2*4624 = 9248
}

__device__ __forceinline__ half2_t pkrtz(float a, float b) {
    return __builtin_bit_cast(half2_t, __builtin_amdgcn_cvt_pkrtz(a, b));
}
__device__ __forceinline__ void wave_fence() {
    asm volatile("s_waitcnt lgkmcnt(0)" ::: "memory");
}

__global__ __launch_bounds__(NT, 3) void patnet_kernel(
    const float* __restrict__ emb,
    const float* __restrict__ conv_w, const float* __restrict__ conv_b,
    const float* __restrict__ ppw_w,  const float* __restrict__ ppw_b,
    const float* __restrict__ pdw_w,  const float* __restrict__ pdw_b,
    const float* __restrict__ pf_w,
    const float* __restrict__ vpw_w,  const float* __restrict__ vpw_b,
    const float* __restrict__ vl1_w,  const float* __restrict__ vl1_b,
    const float* __restrict__ vl2_w,  const float* __restrict__ vl2_b,
    const float* __restrict__ vf_w,   const float* __restrict__ vf_b,
    const int* __restrict__ sparse,   const int* __restrict__ board,
    float* __restrict__ out, int batch)
{
    __shared__ __align__(16) unsigned char smem[SMEM_BYTES];
    const int tid  = threadIdx.x;
    const int b    = blockIdx.x;
    const int lane = tid & 63;
    const int wave = tid >> 6;

    // ---- issue code loads first (deep prefetch) ----
    int c0 = 0, c1 = 0;
    if (tid < NPIX) {
        int s10 = sparse[b * 2700 + 10 * NPIX + tid];
        int s11 = sparse[b * 2700 + 11 * NPIX + tid];
        int b0  = board[b * 450 + tid];
        int b1  = board[b * 450 + NPIX + tid];
        c0 = (b0 > 0) ? PCODE_C : s10;
        c1 = ((b1 > 0) ? PCODE_C : s11) + (PCODE_C + 1);
    }

    // ---- P0: stage depthwise weight tables (transposed) + zero A pads ----
    {
        _Float16* Wc   = (_Float16*)(smem + OFF_WC);
        _Float16* Wcb  = (_Float16*)(smem + OFF_WCB);
        _Float16* Wpd  = (_Float16*)(smem + OFF_WPD);
        _Float16* Wpdb = (_Float16*)(smem + OFF_WPDB);
        for (int i = tid; i < 432; i += NT) {     // Wc[cg][tap][j] = conv_w[(cg*8+j)*9+tap]
            int cg = i / 72, rem = i - cg * 72;
            int t = rem >> 3, j = rem & 7;
            Wc[i] = (_Float16)conv_w[(cg * 8 + j) * 9 + t];
        }
        for (int i = tid; i < 48; i += NT) Wcb[i] = (_Float16)conv_b[i];
        for (int i = tid; i < 144; i += NT) {
            int cg = i / 72, rem = i - cg * 72;
            int t = rem >> 3, j = rem & 7;
            Wpd[i] = (_Float16)pdw_w[(cg * 8 + j) * 9 + t];
        }
        for (int i = tid; i < 16; i += NT) Wpdb[i] = (_Float16)pdw_b[i];
        // zero A_pad borders: 64 slots per cg
        for (int i = tid; i < 384; i += NT) {
            int cg = i >> 6, j = i & 63;
            int row, col;
            if (j < 17)      { row = 0;  col = j; }
            else if (j < 34) { row = 16; col = j - 17; }
            else { int k = j - 34; row = 1 + (k >> 1); col = (k & 1) * 16; }
            *(half8*)(smem + OFF_A + cg * APITCH_CG + row * APITCH_Y + col * 16) = (half8)(_Float16)0.f;
        }
    }

    // ---- P1: embedding gather + sum -> A_pad interior ----
    if (tid < NPIX) {
        const float* e0 = emb + c0 * 48;
        const float* e1 = emb + c1 * 48;
        int y = tid / 15, x = tid - y * 15;
        unsigned char* abase = smem + OFF_A + (y + 1) * APITCH_Y + (x + 1) * 16;
        #pragma unroll
        for (int g = 0; g < 6; g++) {
            f32x4 x0 = *(const f32x4*)(e0 + g * 8);
            f32x4 x1 = *(const f32x4*)(e0 + g * 8 + 4);
            f32x4 y0 = *(const f32x4*)(e1 + g * 8);
            f32x4 y1 = *(const f32x4*)(e1 + g * 8 + 4);
            f32x4 s0 = x0 + y0, s1 = x1 + y1;
            half2_t q0 = pkrtz(s0.x, s0.y), q1 = pkrtz(s0.z, s0.w);
            half2_t q2 = pkrtz(s1.x, s1.y), q3 = pkrtz(s1.z, s1.w);
            half8 hv = {q0[0], q0[1], q1[0], q1[1], q2[0], q2[1], q3[0], q3[1]};
            *(half8*)(abase + g * APITCH_CG) = hv;
        }
    }
    __syncthreads();

    // ---- P2: depthwise 3x3 (48ch) via 5-px strips, padded (no bounds checks) ----
    auto do_strip = [&](int t) {
        int cg = t / 45, rem = t - cg * 45;
        int y = rem / 3, s = rem - y * 3;
        int xs = s * 5;
        const unsigned char* wb = smem + OFF_WC + cg * 144;
        half8 wv[9];
        #pragma unroll
        for (int i = 0; i < 9; i++) wv[i] = *(const half8*)(wb + i * 16);
        half8 bias = *(const half8*)(smem + OFF_WCB + cg * 16);
        half8 acc[5] = {bias, bias, bias, bias, bias};
        const unsigned char* ab = smem + OFF_A + cg * APITCH_CG + y * APITCH_Y + xs * 16;
        #pragma unroll
        for (int c = 0; c < 7; c++) {
            half8 v0 = *(const half8*)(ab + c * 16);
            half8 v1 = *(const half8*)(ab + APITCH_Y + c * 16);
            half8 v2 = *(const half8*)(ab + 2 * APITCH_Y + c * 16);
            #pragma unroll
            for (int o = 0; o < 5; o++) {
                int kx = c - o;
                if (kx >= 0 && kx <= 2) {
                    acc[o] = __builtin_elementwise_fma(v0, wv[kx],     acc[o]);
                    acc[o] = __builtin_elementwise_fma(v1, wv[3 + kx], acc[o]);
                    acc[o] = __builtin_elementwise_fma(v2, wv[6 + kx], acc[o]);
                }
            }
        }
        unsigned char* xw = smem + OFF_X + (y * 15 + xs) * 96 + cg * 16;
        #pragma unroll
        for (int o = 0; o < 5; o++)
            *(half8*)(xw + o * 96) = __builtin_elementwise_max(acc[o], (half8)(_Float16)0.f);
    };
    do_strip(tid);                       // tasks 0..255
    {
        int e = wave * 4 + lane;         // spread the 14 leftovers across waves
        if (lane < 4 && e < 14) do_strip(256 + e);
    }

    // ---- head-weight prefetch by ALL waves (loads fly during barrier drain) ----
    const int n = lane & 15, q = lane >> 4;
    half8 af_p;
    {
        const float* wp = ppw_w + n * 16 + (q & 1) * 8;
        f32x4 w0 = *(const f32x4*)wp, w1 = *(const f32x4*)(wp + 4);
        half8 t = {(_Float16)w0.x, (_Float16)w0.y, (_Float16)w0.z, (_Float16)w0.w,
                   (_Float16)w1.x, (_Float16)w1.y, (_Float16)w1.z, (_Float16)w1.w};
        af_p = (q < 2) ? t : (half8)(_Float16)0.f;   // K zero-pad 16..31
    }
    f32x4 pb = *(const f32x4*)(ppw_b + q * 4);
    half2_t pfh[8];
    #pragma unroll
    for (int j = 0; j < 8; j++) pfh[j] = pkrtz(pf_w[2 * j], pf_w[2 * j + 1]);
    half8 af0, af1;
    {
        const float* wp = vpw_w + n * 32 + q * 8;
        f32x4 w0 = *(const f32x4*)wp, w1 = *(const f32x4*)(wp + 4);
        af0 = half8{(_Float16)w0.x, (_Float16)w0.y, (_Float16)w0.z, (_Float16)w0.w,
                    (_Float16)w1.x, (_Float16)w1.y, (_Float16)w1.z, (_Float16)w1.w};
        const float* wp2 = vpw_w + (16 + n) * 32 + q * 8;
        f32x4 v0 = *(const f32x4*)wp2, v1 = *(const f32x4*)(wp2 + 4);
        af1 = half8{(_Float16)v0.x, (_Float16)v0.y, (_Float16)v0.z, (_Float16)v0.w,
                    (_Float16)v1.x, (_Float16)v1.y, (_Float16)v1.z, (_Float16)v1.w};
    }
    f32x4 vb0 = *(const f32x4*)(vpw_b + q * 4);
    f32x4 vb1 = *(const f32x4*)(vpw_b + 16 + q * 4);
    __syncthreads();

    // ================= head split: no more block barriers =================
    if (wave < 3) {
        // ---------------- policy path (waves 0,1,2) ----------------
        // zero PolA pads (idempotent, each policy wave does all 128)
        #pragma unroll
        for (int i0 = 0; i0 < 2; i0++) {
            int i = i0 * 64 + lane;
            int cg = i >> 6, j = i & 63;
            int row, col;
            if (j < 17)      { row = 0;  col = j; }
            else if (j < 34) { row = 16; col = j - 17; }
            else { int k = j - 34; row = 1 + (k >> 1); col = (k & 1) * 16; }
            *(half8*)(smem + OFF_POLA + cg * APITCH_CG + row * APITCH_Y + col * 16) = (half8)(_Float16)0.f;
        }
        // preload policy dw weights (cg fixed by lane parity across all 3 rounds)
        const int cgp = lane & 1;
        half8 wvp[9];
        #pragma unroll
        for (int t = 0; t < 9; t++) wvp[t] = *(const half8*)(smem + OFF_WPD + cgp * 144 + t * 16);
        half8 biasp = *(const half8*)(smem + OFF_WPDB + cgp * 16);

        // ph3: 1x1 16->16 via MFMA; each wave computes every tile its ph4 rows need
        const int tlo = (wave == 0) ? 0 : ((wave == 1) ? 3 : 8);
        const int thi = (wave == 0) ? 6 : ((wave == 1) ? 11 : 15);
        const int cg3 = q >> 1;
        for (int t = tlo; t < thi; t++) {
            int p = t * 16 + n;
            half8 bf = *(const half8*)(smem + OFF_X + p * 96 + q * 16);
            f32x4 d = __builtin_amdgcn_mfma_f32_16x16x32_f16(af_p, bf, (f32x4)(0.f), 0, 0, 0);
            if (p < NPIX) {
                int y = p / 15, x = p - y * 15;
                half2_t lo = pkrtz(fmaxf(d.x + pb.x, 0.f), fmaxf(d.y + pb.y, 0.f));
                half2_t hi = pkrtz(fmaxf(d.z + pb.z, 0.f), fmaxf(d.w + pb.w, 0.f));
                half4_t hv = {lo[0], lo[1], hi[0], hi[1]};
                *(half4_t*)(smem + OFF_POLA + cg3 * APITCH_CG + (y + 1) * APITCH_Y + (x + 1) * 16 + (q & 1) * 8) = hv;
            }
        }
        wave_fence();

        // ph4+ph5 fused: dw 3x3 + bias + relu + dot(pf) + pair-sum + store
        const int px0 = wave * 75;
        for (int i = 0; i < 3; i++) {
            int idx = i * 64 + lane;
            if (idx < 150) {
                int px = px0 + (idx >> 1);
                int y = px / 15, x = px - y * 15;
                const unsigned char* pbse = smem + OFF_POLA + cgp * APITCH_CG + y * APITCH_Y + x * 16;
                half8 acc = biasp;
                #pragma unroll
                for (int ky = 0; ky < 3; ky++) {
                    acc = __builtin_elementwise_fma(*(const half8*)(pbse + ky * APITCH_Y),      wvp[ky * 3 + 0], acc);
                    acc = __builtin_elementwise_fma(*(const half8*)(pbse + ky * APITCH_Y + 16), wvp[ky * 3 + 1], acc);
                    acc = __builtin_elementwise_fma(*(const half8*)(pbse + ky * APITCH_Y + 32), wvp[ky * 3 + 2], acc);
                }
                acc = __builtin_elementwise_max(acc, (half8)(_Float16)0.f);
                float part = 0.f;
                part = __builtin_amdgcn_fdot2(half2_t{acc[0], acc[1]}, pfh[cgp * 4 + 0], part, false);
                part = __builtin_amdgcn_fdot2(half2_t{acc[2], acc[3]}, pfh[cgp * 4 + 1], part, false);
                part = __builtin_amdgcn_fdot2(half2_t{acc[4], acc[5]}, pfh[cgp * 4 + 2], part, false);
                part = __builtin_amdgcn_fdot2(half2_t{acc[6], acc[7]}, pfh[cgp * 4 + 3], part, false);
                float tot = part + __shfl_xor(part, 1, 64);
                if (cgp == 0) out[3 * batch + b * NPIX + px] = tot;
            }
        }
    } else {
        // ---------------- value path (wave 3, whole head in-wave) ----------------
        f32x4 a0 = {0.f, 0.f, 0.f, 0.f}, a1 = {0.f, 0.f, 0.f, 0.f};
        for (int t = 0; t < 15; t++) {
            int p = t * 16 + n;
            half8 bf = *(const half8*)(smem + OFF_X + p * 96 + 32 + q * 16);
            f32x4 d0 = __builtin_amdgcn_mfma_f32_16x16x32_f16(af0, bf, (f32x4)(0.f), 0, 0, 0);
            f32x4 d1 = __builtin_amdgcn_mfma_f32_16x16x32_f16(af1, bf, (f32x4)(0.f), 0, 0, 0);
            if (p < NPIX) {
                #pragma unroll
                for (int r = 0; r < 4; r++) {
                    a0[r] += fmaxf(d0[r] + vb0[r], 0.f);
                    a1[r] += fmaxf(d1[r] + vb1[r], 0.f);
                }
            }
        }
        #pragma unroll
        for (int s = 1; s < 16; s <<= 1) {
            #pragma unroll
            for (int r = 0; r < 4; r++) {
                a0[r] += __shfl_xor(a0[r], s, 64);
                a1[r] += __shfl_xor(a1[r], s, 64);
            }
        }
        if (n == 0) {
            *(f32x4*)(smem + OFF_SV + q * 16)      = a0 * (1.f / 225.f);
            *(f32x4*)(smem + OFF_SV + 64 + q * 16) = a1 * (1.f / 225.f);
        }
        // prefetch ALL FC weights before the fence (global loads fly past lgkmcnt)
        const int o = lane & 31;
        f32x4 w1r[8], w2r[8], w3r[8];
        float b1v = vl1_b[o], b2v = vl2_b[o], b3v = 0.f;
        #pragma unroll
        for (int g = 0; g < 8; g++) w1r[g] = *(const f32x4*)(vl1_w + o * 32 + g * 4);
        #pragma unroll
        for (int g = 0; g < 8; g++) w2r[g] = *(const f32x4*)(vl2_w + o * 32 + g * 4);
        if (lane < 3) {
            b3v = vf_b[lane];
            #pragma unroll
            for (int g = 0; g < 8; g++) w3r[g] = *(const f32x4*)(vf_w + lane * 32 + g * 4);
        }
        wave_fence();

        float acc1 = b1v;
        #pragma unroll
        for (int g = 0; g < 8; g++) {
            f32x4 sv = *(const f32x4*)(smem + OFF_SV + g * 16);
            acc1 += sv.x * w1r[g].x + sv.y * w1r[g].y + sv.z * w1r[g].z + sv.w * w1r[g].w;
        }
        acc1 = fmaxf(acc1, 0.f);
        if (lane < 32) *(float*)(smem + OFF_H1 + o * 4) = acc1;
        wave_fence();

        float acc2 = b2v;
        #pragma unroll
        for (int g = 0; g < 8; g++) {
            f32x4 hv = *(const f32x4*)(smem + OFF_H1 + g * 16);
            acc2 += hv.x * w2r[g].x + hv.y * w2r[g].y + hv.z * w2r[g].z + hv.w * w2r[g].w;
        }
        acc2 = fmaxf(acc2, 0.f);
        if (lane < 32) *(float*)(smem + OFF_H2 + o * 4) = acc2;
        wave_fence();

        if (lane < 3) {
            float acc3 = b3v;
            #pragma unroll
            for (int g = 0; g < 8; g++) {
                f32x4 hv = *(const f32x4*)(smem + OFF_H2 + g * 16);
                acc3 += hv.x * w3r[g].x + hv.y * w3r[g].y + hv.z * w3r[g].z + hv.w * w3r[g].w;
            }
            out[b * 3 + lane] = acc3;
        }
    }
}

extern "C" void kernel_launch(void* const* d_in, const int* in_sizes, int n_in,
                              void* d_out, int out_size, void* d_ws, size_t ws_size,
                              hipStream_t stream) {
    const float* emb    = (const float*)d_in[0];
    const float* conv_w = (const float*)d_in[1];
    const float* conv_b = (const float*)d_in[2];
    const float* ppw_w  = (const float*)d_in[3];
    const float* ppw_b  = (const float*)d_in[4];
    const float* pdw_w  = (const float*)d_in[5];
    const float* pdw_b  = (const float*)d_in[6];
    const float* pf_w   = (const float*)d_in[7];
    const float* vpw_w  = (const float*)d_in[8];
    const float* vpw_b  = (const float*)d_in[9];
    const float* vl1_w  = (const float*)d_in[10];
    const float* vl1_b  = (const float*)d_in[11];
    const float* vl2_w  = (const float*)d_in[12];
    const float* vl2_b  = (const float*)d_in[13];
    const float* vf_w   = (const float*)d_in[14];
    const float* vf_b   = (const float*)d_in[15];
    const int* sparse   = (const int*)d_in[16];
    const int* board    = (const int*)d_in[17];
    float* out = (float*)d_out;

    int batch = in_sizes[16] / 2700;  // 4096
    patnet_kernel<<<batch, NT, 0, stream>>>(
        emb, conv_w, conv_b, ppw_w, ppw_b, pdw_w, pdw_b, pf_w,
        vpw_w, vpw_b, vl1_w, vl1_b, vl2_w, vl2_b, vf_w, vf_b,
        sparse, board, out, batch);
}